// Round 3
// baseline (362.763 us; speedup 1.0000x reference)
//
#include <hip/hip_runtime.h>
#include <hip/hip_bf16.h>
#include <math.h>

typedef __hip_bfloat16 bf16;
typedef __attribute__((ext_vector_type(4))) float f32x4;
typedef __attribute__((ext_vector_type(8))) short s16x8;

#define NB 8192
#define KP 1120   // padded K: 1089 -> 35*32
#define NP 1152   // padded N: 1089 -> 9*128

struct SubP {
    const float* x; const float* gamma; const float* beta;
    const float* W1; const float* b1; const float* W2; const float* b2;
    const float* W3; const float* b3;
    float* sum; float* sumsq; float* a; float* b1p; float* hout;
    int F;
};
struct SubP3 { SubP s[3]; };

// ---------------- BatchNorm stats (all 3 subnets, one launch) ----------------
__global__ void stats3_kernel(SubP3 P) {
    const SubP p = P.s[blockIdx.z];
    int F = p.F;
    int fl = threadIdx.x & 63;
    int rg = threadIdx.x >> 6;               // 0..3
    int f = blockIdx.x * 64 + fl;
    int rc = blockIdx.y;                     // 32 row chunks of 256
    float s = 0.f, s2 = 0.f;
    if (f < F) {
        int rend = rc * 256 + 256;
        for (int r = rc * 256 + rg; r < rend; r += 4) {
            float v = p.x[(size_t)r * F + f];
            s += v; s2 += v * v;
        }
    }
    __shared__ float l1[4][64], l2[4][64];
    l1[rg][fl] = s; l2[rg][fl] = s2;
    __syncthreads();
    if (rg == 0 && f < F) {
        float S  = l1[0][fl] + l1[1][fl] + l1[2][fl] + l1[3][fl];
        float S2 = l2[0][fl] + l2[1][fl] + l2[2][fl] + l2[3][fl];
        atomicAdd(&p.sum[f], S);
        atomicAdd(&p.sumsq[f], S2);
    }
}

// ---------------- finalize stats + fold bias (one block per subnet) ----------------
__global__ void prep3_kernel(SubP3 P) {
    const SubP p = P.s[blockIdx.x];
    __shared__ float c_sh[1024];
    int t = threadIdx.x;
    for (int f = t; f < p.F; f += 256) {
        float mu  = p.sum[f]   * (1.f / 8192.f);
        float var = p.sumsq[f] * (1.f / 8192.f) - mu * mu;
        float a = p.gamma[f] * rsqrtf(var + 1e-5f);
        p.a[f] = a;
        c_sh[f] = p.beta[f] - mu * a;
    }
    __syncthreads();
    int h = t & 31, g = t >> 5;
    float s = 0.f;
    for (int f = g; f < p.F; f += 8) s += c_sh[f] * p.W1[(size_t)f * 32 + h];
    __shared__ float red[8][33];
    red[g][h] = s;
    __syncthreads();
    if (g == 0) {
        float tot = p.b1[h];
        #pragma unroll
        for (int gg = 0; gg < 8; gg++) tot += red[gg][h];
        p.b1p[h] = tot;
    }
}

// ---------------- Subnet MLP: 64 rows/block, 4h x 4r register tile, k-split 2 ----------------
__global__ void __launch_bounds__(256) subnet3_kernel(SubP3 P) {
    const SubP p = P.s[blockIdx.y];
    const int F = p.F;
    __shared__ float Xt[64][132];     // rows x k-chunk
    __shared__ float Wt[32][132];     // Wt[h][k] for layer1; reused [k][h] for W2/W3
    __shared__ float Red[64][36];     // k-split partials -> H1
    int t = threadIdx.x;
    int row0 = blockIdx.x * 64;
    int kg = t >> 7;                  // 0,1
    int rgrp = (t >> 3) & 15;         // 16 groups x 4 rows
    int hgrp = t & 7;                 // 8 groups x 4 h
    int r0 = rgrp * 4, h0 = hgrp * 4;

    float acc[4][4] = {};             // [hi][ri]

    for (int k0 = 0; k0 < F; k0 += 128) {
        int kc = F - k0; if (kc > 128) kc = 128;
        int kcp = (kc + 3) & ~3;
        __syncthreads();
        if (kc == 128) {
            #pragma unroll
            for (int i = 0; i < 8; i++) {
                int idx = t + i * 256;
                int r = idx >> 5, c4 = (idx & 31) * 4;
                *(float4*)&Xt[r][c4] = *(const float4*)&p.x[(size_t)(row0 + r) * F + k0 + c4];
            }
        } else {
            for (int idx = t; idx < 64 * kcp; idx += 256) {
                int r = idx / kcp, kk = idx - r * kcp;
                Xt[r][kk] = (kk < kc) ? p.x[(size_t)(row0 + r) * F + k0 + kk] : 0.f;
            }
        }
        for (int idx = t; idx < 32 * kcp; idx += 256) {
            int kk = idx >> 5, h = idx & 31;
            Wt[h][kk] = (kk < kc) ? p.a[k0 + kk] * p.W1[(size_t)(k0 + kk) * 32 + h] : 0.f;
        }
        __syncthreads();
        int kb = kg * 64;
        int ke = kb + 64; if (ke > kcp) ke = kcp;
        for (int kk = kb; kk < ke; kk += 4) {
            float4 wv[4], xv[4];
            #pragma unroll
            for (int i = 0; i < 4; i++) wv[i] = *(const float4*)&Wt[h0 + i][kk];
            #pragma unroll
            for (int i = 0; i < 4; i++) xv[i] = *(const float4*)&Xt[r0 + i][kk];
            #pragma unroll
            for (int hi = 0; hi < 4; hi++)
                #pragma unroll
                for (int ri = 0; ri < 4; ri++)
                    acc[hi][ri] = fmaf(wv[hi].x, xv[ri].x, fmaf(wv[hi].y, xv[ri].y,
                                  fmaf(wv[hi].z, xv[ri].z, fmaf(wv[hi].w, xv[ri].w, acc[hi][ri]))));
        }
    }
    // k-split reduction + bias + relu -> H1 in Red[r][h]
    if (kg == 1) {
        #pragma unroll
        for (int hi = 0; hi < 4; hi++)
            #pragma unroll
            for (int ri = 0; ri < 4; ri++)
                Red[r0 + ri][h0 + hi] = acc[hi][ri];
    }
    __syncthreads();
    if (kg == 0) {
        #pragma unroll
        for (int hi = 0; hi < 4; hi++) {
            float b = p.b1p[h0 + hi];
            #pragma unroll
            for (int ri = 0; ri < 4; ri++) {
                float v = acc[hi][ri] + Red[r0 + ri][h0 + hi] + b;
                Red[r0 + ri][h0 + hi] = fmaxf(v, 0.f);
            }
        }
    }
    // stage W2 as Wt[k][h]
    for (int idx = t; idx < 1024; idx += 256) Wt[idx >> 5][idx & 31] = p.W2[idx];
    __syncthreads();
    // layer 2: H2[r][h] -> Xt
    int h = t & 31, rg = t >> 5;      // 8 groups x 8 rows
    {
        float a2[8] = {};
        for (int q = 0; q < 32; q++) {
            float w = Wt[q][h];
            #pragma unroll
            for (int i = 0; i < 8; i++) a2[i] += Red[rg * 8 + i][q] * w;
        }
        float bv = p.b2[h];
        #pragma unroll
        for (int i = 0; i < 8; i++) Xt[rg * 8 + i][h] = fmaxf(a2[i] + bv, 0.f);
    }
    __syncthreads();
    for (int idx = t; idx < 1024; idx += 256) Wt[idx >> 5][idx & 31] = p.W3[idx];
    __syncthreads();
    // layer 3 -> global
    {
        float a3[8] = {};
        for (int q = 0; q < 32; q++) {
            float w = Wt[q][h];
            #pragma unroll
            for (int i = 0; i < 8; i++) a3[i] += Xt[rg * 8 + i][q] * w;
        }
        float bv = p.b3[h];
        #pragma unroll
        for (int i = 0; i < 8; i++)
            p.hout[(size_t)(row0 + rg * 8 + i) * 32 + h] = fmaxf(a3[i] + bv, 0.f);
    }
}

// ---------------- p1 build + W2t transpose, one launch ----------------
__global__ void build_both(const float* __restrict__ mk_h, const float* __restrict__ us_h,
                           bf16* __restrict__ p1,
                           const float* __restrict__ Wf1, bf16* __restrict__ W2t) {
    int blk = blockIdx.x;
    int t = threadIdx.x;
    if (blk < NB) {
        // p1[b, k*33+i] = mk1[b,k]*us1[b,i]
        int b = blk;
        __shared__ float mk1[33], us1[33];
        if (t == 0) { mk1[0] = 1.f; us1[0] = 1.f; }
        if (t < 32) mk1[t + 1] = mk_h[(size_t)b * 32 + t];
        else if (t < 64) us1[t - 31] = us_h[(size_t)b * 32 + (t - 32)];
        __syncthreads();
        if (t < 140) {
            int base = t * 8;
            s16x8 v;
            #pragma unroll
            for (int e = 0; e < 8; e++) {
                int idx = base + e;
                float val = 0.f;
                if (idx < 1089) {
                    int k = idx / 33, i = idx - k * 33;
                    val = mk1[k] * us1[i];
                }
                __hip_bfloat16 hb = __float2bfloat16(val);
                v[e] = *(short*)&hb;
            }
            *(s16x8*)(p1 + (size_t)b * KP + base) = v;
        }
    } else {
        // W2t[j*33+o][k*33+i] = Wf1[k*35937 + j*1089 + i*33 + o]
        int kj = blk - NB;
        int k = kj / 33, j = kj - k * 33;
        __shared__ float tile[1089];
        const float* src = Wf1 + (size_t)k * 35937 + (size_t)j * 1089;  // [i][o] contiguous
        for (int idx = t; idx < 1089; idx += 192) tile[idx] = src[idx];
        __syncthreads();
        for (int idx = t; idx < 1089; idx += 192) {
            int o = idx / 33, i = idx - o * 33;   // i inner -> coalesced writes
            W2t[(size_t)(j * 33 + o) * KP + k * 33 + i] = __float2bfloat16(tile[i * 33 + o]);
        }
    }
}

// ---------------- Main GEMM: S[8192,1152] = p1 @ W2t^T (bf16 MFMA, m97-style) ----------------
__global__ void __launch_bounds__(256) gemm_kernel(const bf16* __restrict__ A,   // [NB][KP]
                                                   const bf16* __restrict__ Bt,  // [NP][KP]
                                                   bf16* __restrict__ S) {       // [NB][NP]
    __shared__ __align__(16) bf16 As[128 * 32];
    __shared__ __align__(16) bf16 Bs[128 * 32];
    int t = threadIdx.x;
    int m0 = blockIdx.x * 128;
    int n0 = blockIdx.y * 128;
    int wave = t >> 6, lane = t & 63;
    int wm = (wave & 1) * 64, wn = (wave >> 1) * 64;
    int fr = lane & 15;            // row within a 16-tile
    int kg = (lane >> 4) * 8;      // k-offset of this lane's 8 elements

    // staging: per instruction, 64 lanes x 16B = 16 rows of 32 bf16 (64B each)
    int lr = lane >> 2;            // 0..15
    int lk = (lane & 3) * 8;       // element offset 0/8/16/24
    const bf16* Ag = A  + (size_t)(m0 + wave * 32 + lr) * KP + lk;
    const bf16* Bg = Bt + (size_t)(n0 + wave * 32 + lr) * KP + lk;
    bf16* AsW = As + wave * 32 * 32;
    bf16* BsW = Bs + wave * 32 * 32;

    f32x4 acc[4][4] = {};

    for (int k0 = 0; k0 < KP; k0 += 32) {
        __syncthreads();
        __builtin_amdgcn_global_load_lds(
            (const __attribute__((address_space(1))) void*)(Ag + k0),
            (__attribute__((address_space(3))) void*)(AsW), 16, 0, 0);
        __builtin_amdgcn_global_load_lds(
            (const __attribute__((address_space(1))) void*)(Ag + k0 + 16 * KP),
            (__attribute__((address_space(3))) void*)(AsW + 16 * 32), 16, 0, 0);
        __builtin_amdgcn_global_load_lds(
            (const __attribute__((address_space(1))) void*)(Bg + k0),
            (__attribute__((address_space(3))) void*)(BsW), 16, 0, 0);
        __builtin_amdgcn_global_load_lds(
            (const __attribute__((address_space(1))) void*)(Bg + k0 + 16 * KP),
            (__attribute__((address_space(3))) void*)(BsW + 16 * 32), 16, 0, 0);
        __syncthreads();
        s16x8 bfr[4];
        #pragma unroll
        for (int nt = 0; nt < 4; nt++)
            bfr[nt] = *(const s16x8*)(Bs + (wn + nt * 16 + fr) * 32 + kg);
        #pragma unroll
        for (int mt = 0; mt < 4; mt++) {
            s16x8 af = *(const s16x8*)(As + (wm + mt * 16 + fr) * 32 + kg);
            #pragma unroll
            for (int nt = 0; nt < 4; nt++)
                acc[mt][nt] = __builtin_amdgcn_mfma_f32_16x16x32_bf16(af, bfr[nt], acc[mt][nt], 0, 0, 0);
        }
    }
    // C/D layout: col = lane&15, row = (lane>>4)*4 + reg
    int col = lane & 15, rowg = (lane >> 4) * 4;
    #pragma unroll
    for (int mt = 0; mt < 4; mt++)
        #pragma unroll
        for (int nt = 0; nt < 4; nt++)
            #pragma unroll
            for (int r = 0; r < 4; r++) {
                int gr = m0 + wm + mt * 16 + rowg + r;
                int gc = n0 + wn + nt * 16 + col;
                S[(size_t)gr * NP + gc] = __float2bfloat16(acc[mt][nt][r]);
            }
}

// ---------------- Epilogue: contract j with cd1, relu, final 33x5 + sigmoid ----------------
__global__ void epilogue_kernel(const bf16* __restrict__ S, const float* __restrict__ cd_h,
                                const float* __restrict__ bf1, const float* __restrict__ Wf2,
                                const float* __restrict__ bf2, float* __restrict__ out) {
    int w = threadIdx.x >> 6;
    int lane = threadIdx.x & 63;
    int b = blockIdx.x * 4 + w;
    __shared__ float cdsh[4][33];
    __shared__ float hsh[4][33];
    if (lane == 0) cdsh[w][0] = 1.f;
    if (lane < 32) cdsh[w][lane + 1] = cd_h[(size_t)b * 32 + lane];
    __syncthreads();
    if (lane < 33) {
        float acc = bf1[lane];
        const bf16* Srow = S + (size_t)b * NP;
        #pragma unroll 3
        for (int j = 0; j < 33; j++)
            acc += cdsh[w][j] * __bfloat162float(Srow[j * 33 + lane]);
        hsh[w][lane] = fmaxf(acc, 0.f);
    }
    __syncthreads();
    if (lane < 5) {
        float o = bf2[lane];
        for (int q = 0; q < 33; q++) o += hsh[w][q] * Wf2[q * 5 + lane];
        out[(size_t)b * 5 + lane] = 1.f / (1.f + expf(-o));
    }
}

extern "C" void kernel_launch(void* const* d_in, const int* in_sizes, int n_in,
                              void* d_out, int out_size, void* d_ws, size_t ws_size,
                              hipStream_t stream) {
    const float* US_x     = (const float*)d_in[0];
    const float* CDFI_x   = (const float*)d_in[1];
    const float* marker_x = (const float*)d_in[2];
    const float* Wf1      = (const float*)d_in[27];
    const float* bf1      = (const float*)d_in[28];
    const float* Wf2      = (const float*)d_in[29];
    const float* bf2      = (const float*)d_in[30];
    float* out = (float*)d_out;

    char* ws = (char*)d_ws;
    size_t off = 0;
    auto alloc = [&](size_t bytes) -> void* {
        void* p = ws + off;
        off = (off + bytes + 255) & ~(size_t)255;
        return p;
    };

    float* stat_big = (float*)alloc(3 * 2048 * sizeof(float));
    float* a_buf[3], *b1p_buf[3], *h_buf[3];
    for (int i = 0; i < 3; i++) {
        a_buf[i]   = (float*)alloc(1024 * 4);
        b1p_buf[i] = (float*)alloc(32 * 4);
        h_buf[i]   = (float*)alloc((size_t)NB * 32 * 4);
    }
    bf16*  p1   = (bf16*)alloc((size_t)NB * KP * 2);
    bf16*  W2t  = (bf16*)alloc((size_t)NP * KP * 2);
    bf16*  S    = (bf16*)alloc((size_t)NB * NP * 2);

    SubP3 P;
    const float* xs[3] = {US_x, CDFI_x, marker_x};
    int Fs[3] = {1024, 1024, 10};
    for (int i = 0; i < 3; i++) {
        int base = 3 + i * 8;
        P.s[i].x     = xs[i];
        P.s[i].gamma = (const float*)d_in[base + 0];
        P.s[i].beta  = (const float*)d_in[base + 1];
        P.s[i].W1    = (const float*)d_in[base + 2];
        P.s[i].b1    = (const float*)d_in[base + 3];
        P.s[i].W2    = (const float*)d_in[base + 4];
        P.s[i].b2    = (const float*)d_in[base + 5];
        P.s[i].W3    = (const float*)d_in[base + 6];
        P.s[i].b3    = (const float*)d_in[base + 7];
        P.s[i].sum   = stat_big + i * 2048;
        P.s[i].sumsq = stat_big + i * 2048 + 1024;
        P.s[i].a     = a_buf[i];
        P.s[i].b1p   = b1p_buf[i];
        P.s[i].hout  = h_buf[i];
        P.s[i].F     = Fs[i];
    }

    float* us_h = h_buf[0];
    float* cd_h = h_buf[1];
    float* mk_h = h_buf[2];

    hipMemsetAsync(stat_big, 0, 3 * 2048 * sizeof(float), stream);
    hipMemsetAsync(W2t, 0, (size_t)NP * KP * 2, stream);

    stats3_kernel<<<dim3(16, 32, 3), 256, 0, stream>>>(P);
    prep3_kernel<<<3, 256, 0, stream>>>(P);
    subnet3_kernel<<<dim3(128, 3), 256, 0, stream>>>(P);

    build_both<<<NB + 1089, 192, 0, stream>>>(mk_h, us_h, p1, Wf1, W2t);

    gemm_kernel<<<dim3(NB / 128, NP / 128), 256, 0, stream>>>(p1, W2t, S);

    epilogue_kernel<<<NB / 4, 256, 0, stream>>>(S, cd_h, bf1, Wf2, bf2, out);
}

// Round 4
// 321.065 us; speedup vs baseline: 1.1299x; 1.1299x over previous
//
#include <hip/hip_runtime.h>
#include <hip/hip_bf16.h>
#include <math.h>

typedef __hip_bfloat16 bf16;
typedef __attribute__((ext_vector_type(4))) float f32x4;
typedef __attribute__((ext_vector_type(8))) short s16x8;

#define NB 8192
#define KP 1120   // padded K: 1089 -> 35*32
#define NP 1152   // padded N: 1089 -> 9*128

struct SubP {
    const float* x; const float* gamma; const float* beta;
    const float* W1; const float* b1; const float* W2; const float* b2;
    const float* W3; const float* b3;
    float* sum; float* sumsq; float* hout;
    int F;
};
struct SubP3 { SubP s[3]; };

// ---------------- BatchNorm stats (all 3 subnets, one launch) ----------------
__global__ void stats3_kernel(SubP3 P) {
    const SubP p = P.s[blockIdx.z];
    int F = p.F;
    int fl = threadIdx.x & 63;
    int rg = threadIdx.x >> 6;               // 0..3
    int f = blockIdx.x * 64 + fl;
    int rc = blockIdx.y;                     // 32 row chunks of 256
    float s = 0.f, s2 = 0.f;
    if (f < F) {
        int rend = rc * 256 + 256;
        for (int r = rc * 256 + rg; r < rend; r += 4) {
            float v = p.x[(size_t)r * F + f];
            s += v; s2 += v * v;
        }
    }
    __shared__ float l1[4][64], l2[4][64];
    l1[rg][fl] = s; l2[rg][fl] = s2;
    __syncthreads();
    if (rg == 0 && f < F) {
        float S  = l1[0][fl] + l1[1][fl] + l1[2][fl] + l1[3][fl];
        float S2 = l2[0][fl] + l2[1][fl] + l2[2][fl] + l2[3][fl];
        atomicAdd(&p.sum[f], S);
        atomicAdd(&p.sumsq[f], S2);
    }
}

// ---------------- Subnet MLP: 64 rows/block, 4h x 8r tile, wave k-split 4 ----------------
// BN prep (a, c, b1p-fold) inlined per block; conflict-free LDS layouts:
//   Wt k-major [k][36]  -> reads Wt[kk][4hg], kk wave-uniform: 8 addrs, 8 banks, bcast  = free
//   Xt row-major [r][132], thread rows r = rg + 8*ri -> addr = 4*rg + kk (mod 32)        = free
__global__ void __launch_bounds__(256) subnet3_kernel(SubP3 P) {
    const SubP p = P.s[blockIdx.y];
    const int F = p.F;
    __shared__ float smem[13056];   // Xt[64][132] (8448) | Wt[128][36] (4608)
    __shared__ float a_sh[1024], c_sh[1024], b1p_sh[32];
    float* Xt  = smem;
    float* Wt  = smem + 8448;
    float* Red  = smem;             // [3][64][33] = 6336   (aliases Xt after K loop)
    float* Redf = smem + 6336;      // [8][32]
    float* H1   = smem + 8448;      // [64][33] = 2112      (aliases Wt)
    float* W23  = smem + 8448 + 2112; // [32][33] = 1056
    float* H2   = smem;             // [64][33]             (aliases Red after it's dead)

    int t = threadIdx.x;
    int row0 = blockIdx.x * 64;
    int kg = t >> 6;                // wave id = k-split slice
    int lane = t & 63;
    int hg = lane & 7, h0 = hg * 4; // 4 h per thread
    int rg = lane >> 3;             // rows rg + 8*ri, ri=0..7

    // per-block BN prep: a = gamma*rsqrt(var+eps), c = beta - mu*a
    for (int f = t; f < F; f += 256) {
        float mu  = p.sum[f]   * (1.f / 8192.f);
        float var = p.sumsq[f] * (1.f / 8192.f) - mu * mu;
        float a = p.gamma[f] * rsqrtf(var + 1e-5f);
        a_sh[f] = a;
        c_sh[f] = p.beta[f] - mu * a;
    }

    float acc[4][8] = {};           // [hi][ri]
    float cf = 0.f;                 // c@W1 fold partial for h = t&31

    for (int k0 = 0; k0 < F; k0 += 128) {
        int kc = F - k0; if (kc > 128) kc = 128;
        int kcp = (kc + 3) & ~3;
        __syncthreads();            // a_sh ready (1st iter) / prev compute done
        if (kc == 128) {
            #pragma unroll
            for (int i = 0; i < 8; i++) {
                int idx = t + i * 256;
                int r = idx >> 5, c4 = (idx & 31) * 4;
                *(f32x4*)&Xt[r * 132 + c4] = *(const f32x4*)&p.x[(size_t)(row0 + r) * F + k0 + c4];
            }
        } else {
            for (int idx = t; idx < 64 * kcp; idx += 256) {
                int r = idx / kcp, kk = idx - r * kcp;
                Xt[r * 132 + kk] = (kk < kc) ? p.x[(size_t)(row0 + r) * F + k0 + kk] : 0.f;
            }
        }
        // stage W k-major + fused c-fold (hh == t&31 since stride 256)
        for (int idx = t; idx < kcp * 32; idx += 256) {
            int kk = idx >> 5, hh = idx & 31;
            float w = 0.f;
            if (kk < kc) {
                float wr = p.W1[(size_t)(k0 + kk) * 32 + hh];
                w = a_sh[k0 + kk] * wr;
                cf += c_sh[k0 + kk] * wr;
            }
            Wt[kk * 36 + hh] = w;
        }
        __syncthreads();
        int kb = kg * 32;
        int ke = kb + 32; if (ke > kcp) ke = kcp;
        for (int kk = kb; kk < ke; kk += 4) {
            f32x4 wv[4], xv[8];
            #pragma unroll
            for (int j = 0; j < 4; j++)  wv[j]  = *(const f32x4*)&Wt[(kk + j) * 36 + h0];
            #pragma unroll
            for (int ri = 0; ri < 8; ri++) xv[ri] = *(const f32x4*)&Xt[(rg + 8 * ri) * 132 + kk];
            #pragma unroll
            for (int j = 0; j < 4; j++)
                #pragma unroll
                for (int hi = 0; hi < 4; hi++) {
                    float w = wv[j][hi];
                    #pragma unroll
                    for (int ri = 0; ri < 8; ri++)
                        acc[hi][ri] = fmaf(w, xv[ri][j], acc[hi][ri]);
                }
        }
    }
    __syncthreads();                             // S1: Xt/Wt free
    if (kg > 0) {
        #pragma unroll
        for (int ri = 0; ri < 8; ri++) {
            int r = rg + 8 * ri;
            f32x4 v = {acc[0][ri], acc[1][ri], acc[2][ri], acc[3][ri]};
            *(f32x4*)&Red[(kg - 1) * 2112 + r * 33 + h0] = v;
        }
    }
    Redf[(t >> 5) * 32 + (t & 31)] = cf;
    __syncthreads();                             // S2
    if (t < 32) {
        float b = p.b1[t];
        #pragma unroll
        for (int g = 0; g < 8; g++) b += Redf[g * 32 + t];
        b1p_sh[t] = b;
    }
    if (kg == 0) {
        #pragma unroll
        for (int ri = 0; ri < 8; ri++) {
            int r = rg + 8 * ri;
            #pragma unroll
            for (int pp = 0; pp < 3; pp++) {
                f32x4 v = *(const f32x4*)&Red[pp * 2112 + r * 33 + h0];
                #pragma unroll
                for (int hi = 0; hi < 4; hi++) acc[hi][ri] += v[hi];
            }
        }
    }
    __syncthreads();                             // S3: b1p visible, Red reads done
    if (kg == 0) {
        #pragma unroll
        for (int ri = 0; ri < 8; ri++) {
            int r = rg + 8 * ri;
            #pragma unroll
            for (int hi = 0; hi < 4; hi++)
                H1[r * 33 + h0 + hi] = fmaxf(acc[hi][ri] + b1p_sh[h0 + hi], 0.f);
        }
    }
    for (int idx = t; idx < 1024; idx += 256) W23[(idx >> 5) * 33 + (idx & 31)] = p.W2[idx];
    __syncthreads();                             // S4: H1 + W2 ready
    int h = t & 31, rq = t >> 5;
    {
        float a2[8] = {};
        for (int q = 0; q < 32; q++) {
            float w = W23[q * 33 + h];
            #pragma unroll
            for (int i = 0; i < 8; i++) a2[i] += H1[(rq * 8 + i) * 33 + q] * w;
        }
        float bv = p.b2[h];
        #pragma unroll
        for (int i = 0; i < 8; i++) H2[(rq * 8 + i) * 33 + h] = fmaxf(a2[i] + bv, 0.f);
    }
    __syncthreads();                             // S5
    for (int idx = t; idx < 1024; idx += 256) W23[(idx >> 5) * 33 + (idx & 31)] = p.W3[idx];
    __syncthreads();                             // S6
    {
        float a3[8] = {};
        for (int q = 0; q < 32; q++) {
            float w = W23[q * 33 + h];
            #pragma unroll
            for (int i = 0; i < 8; i++) a3[i] += H2[(rq * 8 + i) * 33 + q] * w;
        }
        float bv = p.b3[h];
        #pragma unroll
        for (int i = 0; i < 8; i++)
            p.hout[(size_t)(row0 + rq * 8 + i) * 32 + h] = fmaxf(a3[i] + bv, 0.f);
    }
}

// ---------------- p1 build + W2t transpose, one launch ----------------
__global__ void build_both(const float* __restrict__ mk_h, const float* __restrict__ us_h,
                           bf16* __restrict__ p1,
                           const float* __restrict__ Wf1, bf16* __restrict__ W2t) {
    int blk = blockIdx.x;
    int t = threadIdx.x;
    if (blk < NB) {
        int b = blk;
        __shared__ float mk1[33], us1[33];
        if (t == 0) { mk1[0] = 1.f; us1[0] = 1.f; }
        if (t < 32) mk1[t + 1] = mk_h[(size_t)b * 32 + t];
        else if (t < 64) us1[t - 31] = us_h[(size_t)b * 32 + (t - 32)];
        __syncthreads();
        if (t < 140) {
            int base = t * 8;
            s16x8 v;
            #pragma unroll
            for (int e = 0; e < 8; e++) {
                int idx = base + e;
                float val = 0.f;
                if (idx < 1089) {
                    int k = idx / 33, i = idx - k * 33;
                    val = mk1[k] * us1[i];
                }
                __hip_bfloat16 hb = __float2bfloat16(val);
                v[e] = *(short*)&hb;
            }
            *(s16x8*)(p1 + (size_t)b * KP + base) = v;
        }
    } else {
        int kj = blk - NB;
        int k = kj / 33, j = kj - k * 33;
        __shared__ float tile[1089];
        const float* src = Wf1 + (size_t)k * 35937 + (size_t)j * 1089;  // [i][o] contiguous
        for (int idx = t; idx < 1089; idx += 192) tile[idx] = src[idx];
        __syncthreads();
        for (int idx = t; idx < 1089; idx += 192) {
            int o = idx / 33, i = idx - o * 33;
            W2t[(size_t)(j * 33 + o) * KP + k * 33 + i] = __float2bfloat16(tile[i * 33 + o]);
        }
    }
}

// ---------------- Main GEMM: S[8192,1152] = p1 @ W2t^T (bf16 MFMA, m97-style) ----------------
__global__ void __launch_bounds__(256) gemm_kernel(const bf16* __restrict__ A,   // [NB][KP]
                                                   const bf16* __restrict__ Bt,  // [NP][KP]
                                                   bf16* __restrict__ S) {       // [NB][NP]
    __shared__ __align__(16) bf16 As[128 * 32];
    __shared__ __align__(16) bf16 Bs[128 * 32];
    int t = threadIdx.x;
    int m0 = blockIdx.x * 128;
    int n0 = blockIdx.y * 128;
    int wave = t >> 6, lane = t & 63;
    int wm = (wave & 1) * 64, wn = (wave >> 1) * 64;
    int fr = lane & 15;
    int kg = (lane >> 4) * 8;

    int lr = lane >> 2;
    int lk = (lane & 3) * 8;
    const bf16* Ag = A  + (size_t)(m0 + wave * 32 + lr) * KP + lk;
    const bf16* Bg = Bt + (size_t)(n0 + wave * 32 + lr) * KP + lk;
    bf16* AsW = As + wave * 32 * 32;
    bf16* BsW = Bs + wave * 32 * 32;

    f32x4 acc[4][4] = {};

    for (int k0 = 0; k0 < KP; k0 += 32) {
        __syncthreads();
        __builtin_amdgcn_global_load_lds(
            (const __attribute__((address_space(1))) void*)(Ag + k0),
            (__attribute__((address_space(3))) void*)(AsW), 16, 0, 0);
        __builtin_amdgcn_global_load_lds(
            (const __attribute__((address_space(1))) void*)(Ag + k0 + 16 * KP),
            (__attribute__((address_space(3))) void*)(AsW + 16 * 32), 16, 0, 0);
        __builtin_amdgcn_global_load_lds(
            (const __attribute__((address_space(1))) void*)(Bg + k0),
            (__attribute__((address_space(3))) void*)(BsW), 16, 0, 0);
        __builtin_amdgcn_global_load_lds(
            (const __attribute__((address_space(1))) void*)(Bg + k0 + 16 * KP),
            (__attribute__((address_space(3))) void*)(BsW + 16 * 32), 16, 0, 0);
        __syncthreads();
        s16x8 bfr[4];
        #pragma unroll
        for (int nt = 0; nt < 4; nt++)
            bfr[nt] = *(const s16x8*)(Bs + (wn + nt * 16 + fr) * 32 + kg);
        #pragma unroll
        for (int mt = 0; mt < 4; mt++) {
            s16x8 af = *(const s16x8*)(As + (wm + mt * 16 + fr) * 32 + kg);
            #pragma unroll
            for (int nt = 0; nt < 4; nt++)
                acc[mt][nt] = __builtin_amdgcn_mfma_f32_16x16x32_bf16(af, bfr[nt], acc[mt][nt], 0, 0, 0);
        }
    }
    int col = lane & 15, rowg = (lane >> 4) * 4;
    #pragma unroll
    for (int mt = 0; mt < 4; mt++)
        #pragma unroll
        for (int nt = 0; nt < 4; nt++)
            #pragma unroll
            for (int r = 0; r < 4; r++) {
                int gr = m0 + wm + mt * 16 + rowg + r;
                int gc = n0 + wn + nt * 16 + col;
                S[(size_t)gr * NP + gc] = __float2bfloat16(acc[mt][nt][r]);
            }
}

// ---------------- Epilogue: contract j with cd1, relu, final 33x5 + sigmoid ----------------
__global__ void epilogue_kernel(const bf16* __restrict__ S, const float* __restrict__ cd_h,
                                const float* __restrict__ bf1, const float* __restrict__ Wf2,
                                const float* __restrict__ bf2, float* __restrict__ out) {
    int w = threadIdx.x >> 6;
    int lane = threadIdx.x & 63;
    int b = blockIdx.x * 4 + w;
    __shared__ float cdsh[4][33];
    __shared__ float hsh[4][33];
    if (lane == 0) cdsh[w][0] = 1.f;
    if (lane < 32) cdsh[w][lane + 1] = cd_h[(size_t)b * 32 + lane];
    __syncthreads();
    if (lane < 33) {
        float acc = bf1[lane];
        const bf16* Srow = S + (size_t)b * NP;
        #pragma unroll 3
        for (int j = 0; j < 33; j++)
            acc += cdsh[w][j] * __bfloat162float(Srow[j * 33 + lane]);
        hsh[w][lane] = fmaxf(acc, 0.f);
    }
    __syncthreads();
    if (lane < 5) {
        float o = bf2[lane];
        for (int q = 0; q < 33; q++) o += hsh[w][q] * Wf2[q * 5 + lane];
        out[(size_t)b * 5 + lane] = 1.f / (1.f + expf(-o));
    }
}

extern "C" void kernel_launch(void* const* d_in, const int* in_sizes, int n_in,
                              void* d_out, int out_size, void* d_ws, size_t ws_size,
                              hipStream_t stream) {
    const float* US_x     = (const float*)d_in[0];
    const float* CDFI_x   = (const float*)d_in[1];
    const float* marker_x = (const float*)d_in[2];
    const float* Wf1      = (const float*)d_in[27];
    const float* bf1      = (const float*)d_in[28];
    const float* Wf2      = (const float*)d_in[29];
    const float* bf2      = (const float*)d_in[30];
    float* out = (float*)d_out;

    char* ws = (char*)d_ws;
    size_t off = 0;
    auto alloc = [&](size_t bytes) -> void* {
        void* p = ws + off;
        off = (off + bytes + 255) & ~(size_t)255;
        return p;
    };

    float* stat_big = (float*)alloc(3 * 2048 * sizeof(float));
    float* h_buf[3];
    for (int i = 0; i < 3; i++) h_buf[i] = (float*)alloc((size_t)NB * 32 * 4);
    bf16*  p1   = (bf16*)alloc((size_t)NB * KP * 2);
    bf16*  W2t  = (bf16*)alloc((size_t)NP * KP * 2);
    bf16*  S    = (bf16*)alloc((size_t)NB * NP * 2);

    SubP3 P;
    const float* xs[3] = {US_x, CDFI_x, marker_x};
    int Fs[3] = {1024, 1024, 10};
    for (int i = 0; i < 3; i++) {
        int base = 3 + i * 8;
        P.s[i].x     = xs[i];
        P.s[i].gamma = (const float*)d_in[base + 0];
        P.s[i].beta  = (const float*)d_in[base + 1];
        P.s[i].W1    = (const float*)d_in[base + 2];
        P.s[i].b1    = (const float*)d_in[base + 3];
        P.s[i].W2    = (const float*)d_in[base + 4];
        P.s[i].b2    = (const float*)d_in[base + 5];
        P.s[i].W3    = (const float*)d_in[base + 6];
        P.s[i].b3    = (const float*)d_in[base + 7];
        P.s[i].sum   = stat_big + i * 2048;
        P.s[i].sumsq = stat_big + i * 2048 + 1024;
        P.s[i].hout  = h_buf[i];
        P.s[i].F     = Fs[i];
    }

    float* us_h = h_buf[0];
    float* cd_h = h_buf[1];
    float* mk_h = h_buf[2];

    hipMemsetAsync(stat_big, 0, 3 * 2048 * sizeof(float), stream);
    hipMemsetAsync(W2t, 0, (size_t)NP * KP * 2, stream);

    stats3_kernel<<<dim3(16, 32, 3), 256, 0, stream>>>(P);
    subnet3_kernel<<<dim3(128, 3), 256, 0, stream>>>(P);

    build_both<<<NB + 1089, 192, 0, stream>>>(mk_h, us_h, p1, Wf1, W2t);

    gemm_kernel<<<dim3(NB / 128, NP / 128), 256, 0, stream>>>(p1, W2t, S);

    epilogue_kernel<<<NB / 4, 256, 0, stream>>>(S, cd_h, bf1, Wf2, bf2, out);
}

// Round 5
// 316.568 us; speedup vs baseline: 1.1459x; 1.0142x over previous
//
#include <hip/hip_runtime.h>
#include <hip/hip_bf16.h>
#include <math.h>

typedef __hip_bfloat16 bf16;
typedef __attribute__((ext_vector_type(4))) float f32x4;
typedef __attribute__((ext_vector_type(8))) short s16x8;

#define NB 8192
#define KP 1120   // padded K: 1089 -> 35*32
#define NP 1152   // padded N: 1089 -> 9*128

struct SubP {
    const float* x; const float* gamma; const float* beta;
    const float* W1; const float* b1; const float* W2; const float* b2;
    const float* W3; const float* b3;
    float* sum; float* sumsq; float* a; float* b1p; float* hout;
    int F;
};
struct SubP3 { SubP s[3]; };

// ---------------- BatchNorm stats: coalesced column sums ----------------
// 32 rows/block; thread owns 4 consecutive columns (f32x4), 8 atomics at end.
__global__ void __launch_bounds__(256) stats3_kernel(SubP3 P) {
    const SubP p = P.s[blockIdx.z];
    int t = threadIdx.x;
    int row0 = blockIdx.x * 32;
    if (p.F == 1024) {
        f32x4 s = {0.f, 0.f, 0.f, 0.f}, s2 = {0.f, 0.f, 0.f, 0.f};
        const float* xp = p.x + (size_t)row0 * 1024 + t * 4;
        #pragma unroll 8
        for (int r = 0; r < 32; r++) {
            f32x4 v = *(const f32x4*)(xp + (size_t)r * 1024);
            s += v; s2 += v * v;
        }
        int f = t * 4;
        #pragma unroll
        for (int e = 0; e < 4; e++) {
            atomicAdd(&p.sum[f + e], s[e]);
            atomicAdd(&p.sumsq[f + e], s2[e]);
        }
    } else {
        __shared__ float ls[16], ls2[16];
        if (t < 16) { ls[t] = 0.f; ls2[t] = 0.f; }
        __syncthreads();
        int F = p.F;
        for (int idx = t; idx < 32 * F; idx += 256) {
            float v = p.x[(size_t)row0 * F + idx];
            int f = idx % 10;            // row0*F ≡ 0 (mod F)
            atomicAdd(&ls[f], v);
            atomicAdd(&ls2[f], v * v);
        }
        __syncthreads();
        if (t < F) { atomicAdd(&p.sum[t], ls[t]); atomicAdd(&p.sumsq[t], ls2[t]); }
    }
}

// ---------------- finalize stats: a[f], b1p[32] (one block per subnet) ----------------
__global__ void prep3_kernel(SubP3 P) {
    const SubP p = P.s[blockIdx.x];
    __shared__ float c_sh[1024];
    __shared__ float red[8][33];
    int t = threadIdx.x;
    for (int f = t; f < p.F; f += 256) {
        float mu  = p.sum[f]   * (1.f / 8192.f);
        float var = p.sumsq[f] * (1.f / 8192.f) - mu * mu;
        float a = p.gamma[f] * rsqrtf(var + 1e-5f);
        p.a[f] = a;
        c_sh[f] = p.beta[f] - mu * a;
    }
    __syncthreads();
    int h = t & 31, g = t >> 5;
    float s = 0.f;
    for (int f = g; f < p.F; f += 8) s += c_sh[f] * p.W1[(size_t)f * 32 + h];
    red[g][h] = s;
    __syncthreads();
    if (t < 32) {
        float tot = p.b1[t];
        #pragma unroll
        for (int gg = 0; gg < 8; gg++) tot += red[gg][t];
        p.b1p[t] = tot;
    }
}

// ---------------- Subnet MLP: 32 rows/block (512 heavy blocks), 4h x 8r tile ----------------
// k-split 8 = 4 waves x 2 lane-halves (shfl_xor(32) merges halves in-register).
// Conflict-free hot reads: Xt stride 68 rows rg+4i -> banks 4rg(+8ks); Wt stride 36 -> 4hg.
__global__ void __launch_bounds__(256) subnet3_kernel(SubP3 P) {
    const SubP p = P.s[blockIdx.y];
    const int F = p.F;
    __shared__ float smem[5664];
    float* Xt  = smem;            // [32][68] = 2176
    float* Wt  = smem + 2176;     // [64][36] = 2304 (K loop ends at 4480)
    float* Red = smem;            // 3 x [32][36] = 3456
    float* H1  = smem + 3456;     // [32][36] -> 4608
    float* W23 = smem + 4608;     // [32][33] -> 5664
    float* H2  = smem;            // [32][36]

    int t = threadIdx.x;
    int row0 = blockIdx.x * 32;
    int kg = t >> 6;
    int lane = t & 63;
    int hg = lane & 7, h0 = hg * 4;
    int rg = (lane >> 3) & 3;
    int ks = lane >> 5;
    int kbase = (kg * 2 + ks) * 8;

    float acc[4][8] = {};         // [hi][ri], rows rg + 4*ri

    for (int k0 = 0; k0 < F; k0 += 64) {
        int kc = F - k0; if (kc > 64) kc = 64;
        int kcp = (kc + 3) & ~3;
        __syncthreads();
        if (kc == 64) {
            #pragma unroll
            for (int i = 0; i < 2; i++) {
                int idx = t + i * 256;
                int r = idx >> 4, c4 = (idx & 15) * 4;
                *(f32x4*)&Xt[r * 68 + c4] = *(const f32x4*)&p.x[(size_t)(row0 + r) * F + k0 + c4];
            }
            #pragma unroll
            for (int i = 0; i < 2; i++) {
                int idx = t + i * 256;
                int kk = idx >> 3, h4 = (idx & 7) * 4;
                f32x4 w = *(const f32x4*)&p.W1[(size_t)(k0 + kk) * 32 + h4];
                float av = p.a[k0 + kk];
                w *= av;
                *(f32x4*)&Wt[kk * 36 + h4] = w;
            }
        } else {
            for (int idx = t; idx < 32 * kcp; idx += 256) {
                int r = idx / kcp, kk = idx - r * kcp;
                Xt[r * 68 + kk] = (kk < kc) ? p.x[(size_t)(row0 + r) * F + k0 + kk] : 0.f;
            }
            for (int idx = t; idx < kcp * 32; idx += 256) {
                int kk = idx >> 5, hh = idx & 31;
                Wt[kk * 36 + hh] = (kk < kc) ? p.a[k0 + kk] * p.W1[(size_t)(k0 + kk) * 32 + hh] : 0.f;
            }
        }
        __syncthreads();
        #pragma unroll
        for (int s = 0; s < 2; s++) {
            int kk = kbase + s * 4;
            if (kk < kcp) {
                f32x4 wv[4], xv[8];
                #pragma unroll
                for (int j = 0; j < 4; j++)  wv[j]  = *(const f32x4*)&Wt[(kk + j) * 36 + h0];
                #pragma unroll
                for (int ri = 0; ri < 8; ri++) xv[ri] = *(const f32x4*)&Xt[(rg + 4 * ri) * 68 + kk];
                #pragma unroll
                for (int j = 0; j < 4; j++)
                    #pragma unroll
                    for (int hi = 0; hi < 4; hi++) {
                        float w = wv[j][hi];
                        #pragma unroll
                        for (int ri = 0; ri < 8; ri++)
                            acc[hi][ri] = fmaf(w, xv[ri][j], acc[hi][ri]);
                    }
            }
        }
    }
    // merge the two lane-half k-slices in-register
    #pragma unroll
    for (int hi = 0; hi < 4; hi++)
        #pragma unroll
        for (int ri = 0; ri < 8; ri++)
            acc[hi][ri] += __shfl_xor(acc[hi][ri], 32);
    __syncthreads();                              // S1: Xt/Wt dead
    if (kg > 0 && ks == 0) {
        #pragma unroll
        for (int ri = 0; ri < 8; ri++) {
            int r = rg + 4 * ri;
            f32x4 v = {acc[0][ri], acc[1][ri], acc[2][ri], acc[3][ri]};
            *(f32x4*)&Red[(kg - 1) * 1152 + r * 36 + h0] = v;
        }
    }
    for (int idx = t; idx < 1024; idx += 256) W23[(idx >> 5) * 33 + (idx & 31)] = p.W2[idx];
    __syncthreads();                              // S2: Red + W2 ready
    if (kg == 0 && ks == 0) {
        f32x4 b = *(const f32x4*)&p.b1p[h0];
        #pragma unroll
        for (int ri = 0; ri < 8; ri++) {
            int r = rg + 4 * ri;
            f32x4 v = {acc[0][ri], acc[1][ri], acc[2][ri], acc[3][ri]};
            #pragma unroll
            for (int pp = 0; pp < 3; pp++)
                v += *(const f32x4*)&Red[pp * 1152 + r * 36 + h0];
            v += b;
            #pragma unroll
            for (int hi = 0; hi < 4; hi++)
                H1[r * 36 + h0 + hi] = fmaxf(v[hi], 0.f);
        }
    }
    __syncthreads();                              // S3: H1 ready
    int h = t & 31, rq = t >> 5;                  // 8 groups x 4 rows
    {
        float a2[4] = {};
        for (int q = 0; q < 32; q++) {
            float w = W23[q * 33 + h];
            #pragma unroll
            for (int i = 0; i < 4; i++) a2[i] += H1[(rq * 4 + i) * 36 + q] * w;
        }
        float bv = p.b2[h];
        #pragma unroll
        for (int i = 0; i < 4; i++) H2[(rq * 4 + i) * 36 + h] = fmaxf(a2[i] + bv, 0.f);
    }
    __syncthreads();                              // S4: W2 reads done, H2 written
    for (int idx = t; idx < 1024; idx += 256) W23[(idx >> 5) * 33 + (idx & 31)] = p.W3[idx];
    __syncthreads();                              // S5
    {
        float a3[4] = {};
        for (int q = 0; q < 32; q++) {
            float w = W23[q * 33 + h];
            #pragma unroll
            for (int i = 0; i < 4; i++) a3[i] += H2[(rq * 4 + i) * 36 + q] * w;
        }
        float bv = p.b3[h];
        #pragma unroll
        for (int i = 0; i < 4; i++)
            p.hout[(size_t)(row0 + rq * 4 + i) * 32 + h] = fmaxf(a3[i] + bv, 0.f);
    }
}

// ---------------- p1 build + W2t transpose, one launch ----------------
__global__ void build_both(const float* __restrict__ mk_h, const float* __restrict__ us_h,
                           bf16* __restrict__ p1,
                           const float* __restrict__ Wf1, bf16* __restrict__ W2t) {
    int blk = blockIdx.x;
    int t = threadIdx.x;
    if (blk < NB) {
        int b = blk;
        __shared__ float mk1[33], us1[33];
        if (t == 0) { mk1[0] = 1.f; us1[0] = 1.f; }
        if (t < 32) mk1[t + 1] = mk_h[(size_t)b * 32 + t];
        else if (t < 64) us1[t - 31] = us_h[(size_t)b * 32 + (t - 32)];
        __syncthreads();
        if (t < 140) {
            int base = t * 8;
            s16x8 v;
            #pragma unroll
            for (int e = 0; e < 8; e++) {
                int idx = base + e;
                float val = 0.f;
                if (idx < 1089) {
                    int k = idx / 33, i = idx - k * 33;
                    val = mk1[k] * us1[i];
                }
                __hip_bfloat16 hb = __float2bfloat16(val);
                v[e] = *(short*)&hb;
            }
            *(s16x8*)(p1 + (size_t)b * KP + base) = v;
        }
    } else {
        int kj = blk - NB;
        int k = kj / 33, j = kj - k * 33;
        __shared__ float tile[1089];
        const float* src = Wf1 + (size_t)k * 35937 + (size_t)j * 1089;  // [i][o] contiguous
        for (int idx = t; idx < 1089; idx += 192) tile[idx] = src[idx];
        __syncthreads();
        for (int idx = t; idx < 1089; idx += 192) {
            int o = idx / 33, i = idx - o * 33;
            W2t[(size_t)(j * 33 + o) * KP + k * 33 + i] = __float2bfloat16(tile[i * 33 + o]);
        }
    }
}

// ---------------- Main GEMM: S[8192,1152] = p1 @ W2t^T (bf16 MFMA, m97-style) ----------------
__global__ void __launch_bounds__(256) gemm_kernel(const bf16* __restrict__ A,   // [NB][KP]
                                                   const bf16* __restrict__ Bt,  // [NP][KP]
                                                   bf16* __restrict__ S) {       // [NB][NP]
    __shared__ __align__(16) bf16 As[128 * 32];
    __shared__ __align__(16) bf16 Bs[128 * 32];
    int t = threadIdx.x;
    int m0 = blockIdx.x * 128;
    int n0 = blockIdx.y * 128;
    int wave = t >> 6, lane = t & 63;
    int wm = (wave & 1) * 64, wn = (wave >> 1) * 64;
    int fr = lane & 15;
    int kg = (lane >> 4) * 8;

    int lr = lane >> 2;
    int lk = (lane & 3) * 8;
    const bf16* Ag = A  + (size_t)(m0 + wave * 32 + lr) * KP + lk;
    const bf16* Bg = Bt + (size_t)(n0 + wave * 32 + lr) * KP + lk;
    bf16* AsW = As + wave * 32 * 32;
    bf16* BsW = Bs + wave * 32 * 32;

    f32x4 acc[4][4] = {};

    for (int k0 = 0; k0 < KP; k0 += 32) {
        __syncthreads();
        __builtin_amdgcn_global_load_lds(
            (const __attribute__((address_space(1))) void*)(Ag + k0),
            (__attribute__((address_space(3))) void*)(AsW), 16, 0, 0);
        __builtin_amdgcn_global_load_lds(
            (const __attribute__((address_space(1))) void*)(Ag + k0 + 16 * KP),
            (__attribute__((address_space(3))) void*)(AsW + 16 * 32), 16, 0, 0);
        __builtin_amdgcn_global_load_lds(
            (const __attribute__((address_space(1))) void*)(Bg + k0),
            (__attribute__((address_space(3))) void*)(BsW), 16, 0, 0);
        __builtin_amdgcn_global_load_lds(
            (const __attribute__((address_space(1))) void*)(Bg + k0 + 16 * KP),
            (__attribute__((address_space(3))) void*)(BsW + 16 * 32), 16, 0, 0);
        __syncthreads();
        s16x8 bfr[4];
        #pragma unroll
        for (int nt = 0; nt < 4; nt++)
            bfr[nt] = *(const s16x8*)(Bs + (wn + nt * 16 + fr) * 32 + kg);
        #pragma unroll
        for (int mt = 0; mt < 4; mt++) {
            s16x8 af = *(const s16x8*)(As + (wm + mt * 16 + fr) * 32 + kg);
            #pragma unroll
            for (int nt = 0; nt < 4; nt++)
                acc[mt][nt] = __builtin_amdgcn_mfma_f32_16x16x32_bf16(af, bfr[nt], acc[mt][nt], 0, 0, 0);
        }
    }
    int col = lane & 15, rowg = (lane >> 4) * 4;
    #pragma unroll
    for (int mt = 0; mt < 4; mt++)
        #pragma unroll
        for (int nt = 0; nt < 4; nt++)
            #pragma unroll
            for (int r = 0; r < 4; r++) {
                int gr = m0 + wm + mt * 16 + rowg + r;
                int gc = n0 + wn + nt * 16 + col;
                S[(size_t)gr * NP + gc] = __float2bfloat16(acc[mt][nt][r]);
            }
}

// ---------------- Epilogue: contract j with cd1, relu, final 33x5 + sigmoid ----------------
__global__ void epilogue_kernel(const bf16* __restrict__ S, const float* __restrict__ cd_h,
                                const float* __restrict__ bf1, const float* __restrict__ Wf2,
                                const float* __restrict__ bf2, float* __restrict__ out) {
    int w = threadIdx.x >> 6;
    int lane = threadIdx.x & 63;
    int b = blockIdx.x * 4 + w;
    __shared__ float cdsh[4][33];
    __shared__ float hsh[4][33];
    if (lane == 0) cdsh[w][0] = 1.f;
    if (lane < 32) cdsh[w][lane + 1] = cd_h[(size_t)b * 32 + lane];
    __syncthreads();
    if (lane < 33) {
        float acc = bf1[lane];
        const bf16* Srow = S + (size_t)b * NP;
        #pragma unroll 3
        for (int j = 0; j < 33; j++)
            acc += cdsh[w][j] * __bfloat162float(Srow[j * 33 + lane]);
        hsh[w][lane] = fmaxf(acc, 0.f);
    }
    __syncthreads();
    if (lane < 5) {
        float o = bf2[lane];
        for (int q = 0; q < 33; q++) o += hsh[w][q] * Wf2[q * 5 + lane];
        out[(size_t)b * 5 + lane] = 1.f / (1.f + expf(-o));
    }
}

extern "C" void kernel_launch(void* const* d_in, const int* in_sizes, int n_in,
                              void* d_out, int out_size, void* d_ws, size_t ws_size,
                              hipStream_t stream) {
    const float* US_x     = (const float*)d_in[0];
    const float* CDFI_x   = (const float*)d_in[1];
    const float* marker_x = (const float*)d_in[2];
    const float* Wf1      = (const float*)d_in[27];
    const float* bf1      = (const float*)d_in[28];
    const float* Wf2      = (const float*)d_in[29];
    const float* bf2      = (const float*)d_in[30];
    float* out = (float*)d_out;

    char* ws = (char*)d_ws;
    size_t off = 0;
    auto alloc = [&](size_t bytes) -> void* {
        void* p = ws + off;
        off = (off + bytes + 255) & ~(size_t)255;
        return p;
    };

    float* stat_big = (float*)alloc(3 * 2048 * sizeof(float));
    float* a_buf[3], *b1p_buf[3], *h_buf[3];
    for (int i = 0; i < 3; i++) {
        a_buf[i]   = (float*)alloc(1024 * 4);
        b1p_buf[i] = (float*)alloc(32 * 4);
        h_buf[i]   = (float*)alloc((size_t)NB * 32 * 4);
    }
    bf16*  p1   = (bf16*)alloc((size_t)NB * KP * 2);
    bf16*  W2t  = (bf16*)alloc((size_t)NP * KP * 2);
    bf16*  S    = (bf16*)alloc((size_t)NB * NP * 2);

    SubP3 P;
    const float* xs[3] = {US_x, CDFI_x, marker_x};
    int Fs[3] = {1024, 1024, 10};
    for (int i = 0; i < 3; i++) {
        int base = 3 + i * 8;
        P.s[i].x     = xs[i];
        P.s[i].gamma = (const float*)d_in[base + 0];
        P.s[i].beta  = (const float*)d_in[base + 1];
        P.s[i].W1    = (const float*)d_in[base + 2];
        P.s[i].b1    = (const float*)d_in[base + 3];
        P.s[i].W2    = (const float*)d_in[base + 4];
        P.s[i].b2    = (const float*)d_in[base + 5];
        P.s[i].W3    = (const float*)d_in[base + 6];
        P.s[i].b3    = (const float*)d_in[base + 7];
        P.s[i].sum   = stat_big + i * 2048;
        P.s[i].sumsq = stat_big + i * 2048 + 1024;
        P.s[i].a     = a_buf[i];
        P.s[i].b1p   = b1p_buf[i];
        P.s[i].hout  = h_buf[i];
        P.s[i].F     = Fs[i];
    }

    float* us_h = h_buf[0];
    float* cd_h = h_buf[1];
    float* mk_h = h_buf[2];

    hipMemsetAsync(stat_big, 0, 3 * 2048 * sizeof(float), stream);
    hipMemsetAsync(W2t, 0, (size_t)NP * KP * 2, stream);

    stats3_kernel<<<dim3(256, 1, 3), 256, 0, stream>>>(P);
    prep3_kernel<<<3, 256, 0, stream>>>(P);
    subnet3_kernel<<<dim3(256, 3), 256, 0, stream>>>(P);

    build_both<<<NB + 1089, 192, 0, stream>>>(mk_h, us_h, p1, Wf1, W2t);

    gemm_kernel<<<dim3(NB / 128, NP / 128), 256, 0, stream>>>(p1, W2t, S);

    epilogue_kernel<<<NB / 4, 256, 0, stream>>>(S, cd_h, bf1, Wf2, bf2, out);
}

// Round 6
// 270.820 us; speedup vs baseline: 1.3395x; 1.1689x over previous
//
#include <hip/hip_runtime.h>
#include <hip/hip_bf16.h>
#include <math.h>

typedef __hip_bfloat16 bf16;
typedef __attribute__((ext_vector_type(4))) float f32x4;
typedef __attribute__((ext_vector_type(8))) short s16x8;

#define NB 8192
#define KP 1120   // padded K: 1089 -> 35*32
#define NP 1152   // padded N: 1089 -> 9*128

struct SubP {
    const float* x; const float* gamma; const float* beta;
    const float* W1; const float* b1; const float* W2; const float* b2;
    const float* W3; const float* b3;
    float* sum; float* sumsq; float* a; float* b1p; float* hout;
    int F;
};
struct SubP3 { SubP s[3]; };

// ---------------- BatchNorm stats: 128 rows/block, coalesced f32x4 streams ----------------
__global__ void __launch_bounds__(256) stats3_kernel(SubP3 P) {
    const SubP p = P.s[blockIdx.z];
    int t = threadIdx.x;
    int row0 = blockIdx.x * 128;
    if (p.F == 1024) {
        f32x4 s = {0.f, 0.f, 0.f, 0.f}, s2 = {0.f, 0.f, 0.f, 0.f};
        const float* xp = p.x + (size_t)row0 * 1024 + t * 4;
        #pragma unroll 8
        for (int r = 0; r < 128; r++) {
            f32x4 v = *(const f32x4*)(xp + (size_t)r * 1024);
            s += v; s2 += v * v;
        }
        int f = t * 4;
        #pragma unroll
        for (int e = 0; e < 4; e++) {
            atomicAdd(&p.sum[f + e], s[e]);
            atomicAdd(&p.sumsq[f + e], s2[e]);
        }
    } else {
        __shared__ float ls[16], ls2[16];
        if (t < 16) { ls[t] = 0.f; ls2[t] = 0.f; }
        __syncthreads();
        int F = p.F;
        for (int idx = t; idx < 128 * F; idx += 256) {
            float v = p.x[(size_t)row0 * F + idx];
            int f = idx % 10;            // row0*F ≡ 0 (mod F)
            atomicAdd(&ls[f], v);
            atomicAdd(&ls2[f], v * v);
        }
        __syncthreads();
        if (t < F) { atomicAdd(&p.sum[t], ls[t]); atomicAdd(&p.sumsq[t], ls2[t]); }
    }
}

// ---------------- finalize stats: a[f]; partial c@W1 fold -> atomic b1p ----------------
// grid (32, 3): block owns 32 f-values. b1p is a zeroed accumulator; b1 added at use.
__global__ void prep3_kernel(SubP3 P) {
    const SubP p = P.s[blockIdx.y];
    int f0 = blockIdx.x * 32;
    if (f0 >= p.F) return;
    int t = threadIdx.x;
    __shared__ float c_sh[32];
    __shared__ float red[8][33];
    int fc = p.F - f0; if (fc > 32) fc = 32;
    if (t < 32) {
        float c = 0.f;
        if (t < fc) {
            int f = f0 + t;
            float mu  = p.sum[f]   * (1.f / 8192.f);
            float var = p.sumsq[f] * (1.f / 8192.f) - mu * mu;
            float a = p.gamma[f] * rsqrtf(var + 1e-5f);
            p.a[f] = a;
            c = p.beta[f] - mu * a;
        }
        c_sh[t] = c;
    }
    __syncthreads();
    int h = t & 31, g = t >> 5;
    float s = 0.f;
    for (int fi = g; fi < fc; fi += 8)
        s += c_sh[fi] * p.W1[(size_t)(f0 + fi) * 32 + h];
    red[g][h] = s;
    __syncthreads();
    if (t < 32) {
        float tot = 0.f;
        #pragma unroll
        for (int gg = 0; gg < 8; gg++) tot += red[gg][t];
        atomicAdd(&p.b1p[t], tot);
    }
}

// ---------------- Subnet MLP: 32 rows/block (512 heavy blocks), 4h x 8r tile ----------------
// k-split 8 = 4 waves x 2 lane-halves (shfl_xor(32) merges halves in-register).
// Conflict-free hot reads: Xt stride 68 rows rg+4i -> banks 4rg(+8ks); Wt stride 36 -> 4hg.
__global__ void __launch_bounds__(256) subnet3_kernel(SubP3 P) {
    const SubP p = P.s[blockIdx.y];
    const int F = p.F;
    __shared__ float smem[5664];
    float* Xt  = smem;            // [32][68] = 2176
    float* Wt  = smem + 2176;     // [64][36] = 2304 (K loop ends at 4480)
    float* Red = smem;            // 3 x [32][36] = 3456
    float* H1  = smem + 3456;     // [32][36] -> 4608
    float* W23 = smem + 4608;     // [32][33] -> 5664
    float* H2  = smem;            // [32][36]

    int t = threadIdx.x;
    int row0 = blockIdx.x * 32;
    int kg = t >> 6;
    int lane = t & 63;
    int hg = lane & 7, h0 = hg * 4;
    int rg = (lane >> 3) & 3;
    int ks = lane >> 5;
    int kbase = (kg * 2 + ks) * 8;

    float acc[4][8] = {};         // [hi][ri], rows rg + 4*ri

    for (int k0 = 0; k0 < F; k0 += 64) {
        int kc = F - k0; if (kc > 64) kc = 64;
        int kcp = (kc + 3) & ~3;
        __syncthreads();
        if (kc == 64) {
            #pragma unroll
            for (int i = 0; i < 2; i++) {
                int idx = t + i * 256;
                int r = idx >> 4, c4 = (idx & 15) * 4;
                *(f32x4*)&Xt[r * 68 + c4] = *(const f32x4*)&p.x[(size_t)(row0 + r) * F + k0 + c4];
            }
            #pragma unroll
            for (int i = 0; i < 2; i++) {
                int idx = t + i * 256;
                int kk = idx >> 3, h4 = (idx & 7) * 4;
                f32x4 w = *(const f32x4*)&p.W1[(size_t)(k0 + kk) * 32 + h4];
                float av = p.a[k0 + kk];
                w *= av;
                *(f32x4*)&Wt[kk * 36 + h4] = w;
            }
        } else {
            for (int idx = t; idx < 32 * kcp; idx += 256) {
                int r = idx / kcp, kk = idx - r * kcp;
                Xt[r * 68 + kk] = (kk < kc) ? p.x[(size_t)(row0 + r) * F + k0 + kk] : 0.f;
            }
            for (int idx = t; idx < kcp * 32; idx += 256) {
                int kk = idx >> 5, hh = idx & 31;
                Wt[kk * 36 + hh] = (kk < kc) ? p.a[k0 + kk] * p.W1[(size_t)(k0 + kk) * 32 + hh] : 0.f;
            }
        }
        __syncthreads();
        #pragma unroll
        for (int s = 0; s < 2; s++) {
            int kk = kbase + s * 4;
            if (kk < kcp) {
                f32x4 wv[4], xv[8];
                #pragma unroll
                for (int j = 0; j < 4; j++)  wv[j]  = *(const f32x4*)&Wt[(kk + j) * 36 + h0];
                #pragma unroll
                for (int ri = 0; ri < 8; ri++) xv[ri] = *(const f32x4*)&Xt[(rg + 4 * ri) * 68 + kk];
                #pragma unroll
                for (int j = 0; j < 4; j++)
                    #pragma unroll
                    for (int hi = 0; hi < 4; hi++) {
                        float w = wv[j][hi];
                        #pragma unroll
                        for (int ri = 0; ri < 8; ri++)
                            acc[hi][ri] = fmaf(w, xv[ri][j], acc[hi][ri]);
                    }
            }
        }
    }
    // merge the two lane-half k-slices in-register
    #pragma unroll
    for (int hi = 0; hi < 4; hi++)
        #pragma unroll
        for (int ri = 0; ri < 8; ri++)
            acc[hi][ri] += __shfl_xor(acc[hi][ri], 32);
    __syncthreads();                              // S1: Xt/Wt dead
    if (kg > 0 && ks == 0) {
        #pragma unroll
        for (int ri = 0; ri < 8; ri++) {
            int r = rg + 4 * ri;
            f32x4 v = {acc[0][ri], acc[1][ri], acc[2][ri], acc[3][ri]};
            *(f32x4*)&Red[(kg - 1) * 1152 + r * 36 + h0] = v;
        }
    }
    for (int idx = t; idx < 1024; idx += 256) W23[(idx >> 5) * 33 + (idx & 31)] = p.W2[idx];
    __syncthreads();                              // S2: Red + W2 ready
    if (kg == 0 && ks == 0) {
        f32x4 b;
        #pragma unroll
        for (int hi = 0; hi < 4; hi++) b[hi] = p.b1[h0 + hi] + p.b1p[h0 + hi];
        #pragma unroll
        for (int ri = 0; ri < 8; ri++) {
            int r = rg + 4 * ri;
            f32x4 v = {acc[0][ri], acc[1][ri], acc[2][ri], acc[3][ri]};
            #pragma unroll
            for (int pp = 0; pp < 3; pp++)
                v += *(const f32x4*)&Red[pp * 1152 + r * 36 + h0];
            v += b;
            #pragma unroll
            for (int hi = 0; hi < 4; hi++)
                H1[r * 36 + h0 + hi] = fmaxf(v[hi], 0.f);
        }
    }
    __syncthreads();                              // S3: H1 ready
    int h = t & 31, rq = t >> 5;                  // 8 groups x 4 rows
    {
        float a2[4] = {};
        for (int q = 0; q < 32; q++) {
            float w = W23[q * 33 + h];
            #pragma unroll
            for (int i = 0; i < 4; i++) a2[i] += H1[(rq * 4 + i) * 36 + q] * w;
        }
        float bv = p.b2[h];
        #pragma unroll
        for (int i = 0; i < 4; i++) H2[(rq * 4 + i) * 36 + h] = fmaxf(a2[i] + bv, 0.f);
    }
    __syncthreads();                              // S4: W2 reads done, H2 written
    for (int idx = t; idx < 1024; idx += 256) W23[(idx >> 5) * 33 + (idx & 31)] = p.W3[idx];
    __syncthreads();                              // S5
    {
        float a3[4] = {};
        for (int q = 0; q < 32; q++) {
            float w = W23[q * 33 + h];
            #pragma unroll
            for (int i = 0; i < 4; i++) a3[i] += H2[(rq * 4 + i) * 36 + q] * w;
        }
        float bv = p.b3[h];
        #pragma unroll
        for (int i = 0; i < 4; i++)
            p.hout[(size_t)(row0 + rq * 4 + i) * 32 + h] = fmaxf(a3[i] + bv, 0.f);
    }
}

// ---------------- p1 build + W2t transpose, one launch ----------------
__global__ void build_both(const float* __restrict__ mk_h, const float* __restrict__ us_h,
                           bf16* __restrict__ p1,
                           const float* __restrict__ Wf1, bf16* __restrict__ W2t) {
    int blk = blockIdx.x;
    int t = threadIdx.x;
    if (blk < NB) {
        int b = blk;
        __shared__ float mk1[33], us1[33];
        if (t == 0) { mk1[0] = 1.f; us1[0] = 1.f; }
        if (t < 32) mk1[t + 1] = mk_h[(size_t)b * 32 + t];
        else if (t < 64) us1[t - 31] = us_h[(size_t)b * 32 + (t - 32)];
        __syncthreads();
        if (t < 140) {
            int base = t * 8;
            s16x8 v;
            #pragma unroll
            for (int e = 0; e < 8; e++) {
                int idx = base + e;
                float val = 0.f;
                if (idx < 1089) {
                    int k = idx / 33, i = idx - k * 33;
                    val = mk1[k] * us1[i];
                }
                __hip_bfloat16 hb = __float2bfloat16(val);
                v[e] = *(short*)&hb;
            }
            *(s16x8*)(p1 + (size_t)b * KP + base) = v;
        }
    } else {
        int kj = blk - NB;
        int k = kj / 33, j = kj - k * 33;
        __shared__ float tile[1089];
        const float* src = Wf1 + (size_t)k * 35937 + (size_t)j * 1089;  // [i][o] contiguous
        for (int idx = t; idx < 1089; idx += 192) tile[idx] = src[idx];
        __syncthreads();
        for (int idx = t; idx < 1089; idx += 192) {
            int o = idx / 33, i = idx - o * 33;
            W2t[(size_t)(j * 33 + o) * KP + k * 33 + i] = __float2bfloat16(tile[i * 33 + o]);
        }
    }
}

// ---------------- Main GEMM: S[8192,1152] = p1 @ W2t^T (bf16 MFMA, m97-style) ----------------
__global__ void __launch_bounds__(256) gemm_kernel(const bf16* __restrict__ A,   // [NB][KP]
                                                   const bf16* __restrict__ Bt,  // [NP][KP]
                                                   bf16* __restrict__ S) {       // [NB][NP]
    __shared__ __align__(16) bf16 As[128 * 32];
    __shared__ __align__(16) bf16 Bs[128 * 32];
    int t = threadIdx.x;
    int m0 = blockIdx.x * 128;
    int n0 = blockIdx.y * 128;
    int wave = t >> 6, lane = t & 63;
    int wm = (wave & 1) * 64, wn = (wave >> 1) * 64;
    int fr = lane & 15;
    int kg = (lane >> 4) * 8;

    int lr = lane >> 2;
    int lk = (lane & 3) * 8;
    const bf16* Ag = A  + (size_t)(m0 + wave * 32 + lr) * KP + lk;
    const bf16* Bg = Bt + (size_t)(n0 + wave * 32 + lr) * KP + lk;
    bf16* AsW = As + wave * 32 * 32;
    bf16* BsW = Bs + wave * 32 * 32;

    f32x4 acc[4][4] = {};

    for (int k0 = 0; k0 < KP; k0 += 32) {
        __syncthreads();
        __builtin_amdgcn_global_load_lds(
            (const __attribute__((address_space(1))) void*)(Ag + k0),
            (__attribute__((address_space(3))) void*)(AsW), 16, 0, 0);
        __builtin_amdgcn_global_load_lds(
            (const __attribute__((address_space(1))) void*)(Ag + k0 + 16 * KP),
            (__attribute__((address_space(3))) void*)(AsW + 16 * 32), 16, 0, 0);
        __builtin_amdgcn_global_load_lds(
            (const __attribute__((address_space(1))) void*)(Bg + k0),
            (__attribute__((address_space(3))) void*)(BsW), 16, 0, 0);
        __builtin_amdgcn_global_load_lds(
            (const __attribute__((address_space(1))) void*)(Bg + k0 + 16 * KP),
            (__attribute__((address_space(3))) void*)(BsW + 16 * 32), 16, 0, 0);
        __syncthreads();
        s16x8 bfr[4];
        #pragma unroll
        for (int nt = 0; nt < 4; nt++)
            bfr[nt] = *(const s16x8*)(Bs + (wn + nt * 16 + fr) * 32 + kg);
        #pragma unroll
        for (int mt = 0; mt < 4; mt++) {
            s16x8 af = *(const s16x8*)(As + (wm + mt * 16 + fr) * 32 + kg);
            #pragma unroll
            for (int nt = 0; nt < 4; nt++)
                acc[mt][nt] = __builtin_amdgcn_mfma_f32_16x16x32_bf16(af, bfr[nt], acc[mt][nt], 0, 0, 0);
        }
    }
    int col = lane & 15, rowg = (lane >> 4) * 4;
    #pragma unroll
    for (int mt = 0; mt < 4; mt++)
        #pragma unroll
        for (int nt = 0; nt < 4; nt++)
            #pragma unroll
            for (int r = 0; r < 4; r++) {
                int gr = m0 + wm + mt * 16 + rowg + r;
                int gc = n0 + wn + nt * 16 + col;
                S[(size_t)gr * NP + gc] = __float2bfloat16(acc[mt][nt][r]);
            }
}

// ---------------- Epilogue: stage S rows coalesced, contract j, 33x5 + sigmoid ----------------
__global__ void __launch_bounds__(256) epilogue_kernel(const bf16* __restrict__ S,
                                const float* __restrict__ cd_h,
                                const float* __restrict__ bf1, const float* __restrict__ Wf2,
                                const float* __restrict__ bf2, float* __restrict__ out) {
    int w = threadIdx.x >> 6;
    int lane = threadIdx.x & 63;
    int b = blockIdx.x * 4 + w;
    __shared__ float Sl[4][1152];
    __shared__ float cdsh[4][33];
    __shared__ float hsh[4][40];
    // coalesced stage: wave reads its row as 16B chunks (144 chunks of 8 bf16)
    const bf16* Srow = S + (size_t)b * NP;
    #pragma unroll
    for (int pass = 0; pass < 3; pass++) {
        int idx = lane + pass * 64;
        if (idx < 144) {
            s16x8 v = *(const s16x8*)(Srow + idx * 8);
            #pragma unroll
            for (int e = 0; e < 8; e++) {
                short sv = v[e];
                Sl[w][idx * 8 + e] = __bfloat162float(*(bf16*)&sv);
            }
        }
    }
    if (lane == 0) cdsh[w][0] = 1.f;
    if (lane < 32) cdsh[w][lane + 1] = cd_h[(size_t)b * 32 + lane];
    __syncthreads();
    if (lane < 33) {
        float acc = bf1[lane];
        #pragma unroll 3
        for (int j = 0; j < 33; j++)
            acc += cdsh[w][j] * Sl[w][j * 33 + lane];
        hsh[w][lane] = fmaxf(acc, 0.f);
    }
    __syncthreads();
    if (lane < 5) {
        float o = bf2[lane];
        for (int q = 0; q < 33; q++) o += hsh[w][q] * Wf2[q * 5 + lane];
        out[(size_t)b * 5 + lane] = 1.f / (1.f + expf(-o));
    }
}

extern "C" void kernel_launch(void* const* d_in, const int* in_sizes, int n_in,
                              void* d_out, int out_size, void* d_ws, size_t ws_size,
                              hipStream_t stream) {
    const float* US_x     = (const float*)d_in[0];
    const float* CDFI_x   = (const float*)d_in[1];
    const float* marker_x = (const float*)d_in[2];
    const float* Wf1      = (const float*)d_in[27];
    const float* bf1      = (const float*)d_in[28];
    const float* Wf2      = (const float*)d_in[29];
    const float* bf2      = (const float*)d_in[30];
    float* out = (float*)d_out;

    char* ws = (char*)d_ws;
    size_t off = 0;
    auto alloc = [&](size_t bytes) -> void* {
        void* p = ws + off;
        off = (off + bytes + 255) & ~(size_t)255;
        return p;
    };

    // per subnet: sum[1024] | sumsq[1024] | b1p_acc[128]  (all zeroed)
    float* stat_big = (float*)alloc(3 * 2176 * sizeof(float));
    float* a_buf[3], *h_buf[3];
    for (int i = 0; i < 3; i++) {
        a_buf[i] = (float*)alloc(1024 * 4);
        h_buf[i] = (float*)alloc((size_t)NB * 32 * 4);
    }
    bf16*  p1   = (bf16*)alloc((size_t)NB * KP * 2);
    bf16*  W2t  = (bf16*)alloc((size_t)NP * KP * 2);
    bf16*  S    = (bf16*)alloc((size_t)NB * NP * 2);

    SubP3 P;
    const float* xs[3] = {US_x, CDFI_x, marker_x};
    int Fs[3] = {1024, 1024, 10};
    for (int i = 0; i < 3; i++) {
        int base = 3 + i * 8;
        P.s[i].x     = xs[i];
        P.s[i].gamma = (const float*)d_in[base + 0];
        P.s[i].beta  = (const float*)d_in[base + 1];
        P.s[i].W1    = (const float*)d_in[base + 2];
        P.s[i].b1    = (const float*)d_in[base + 3];
        P.s[i].W2    = (const float*)d_in[base + 4];
        P.s[i].b2    = (const float*)d_in[base + 5];
        P.s[i].W3    = (const float*)d_in[base + 6];
        P.s[i].b3    = (const float*)d_in[base + 7];
        P.s[i].sum   = stat_big + i * 2176;
        P.s[i].sumsq = stat_big + i * 2176 + 1024;
        P.s[i].b1p   = stat_big + i * 2176 + 2048;
        P.s[i].a     = a_buf[i];
        P.s[i].hout  = h_buf[i];
        P.s[i].F     = Fs[i];
    }

    float* us_h = h_buf[0];
    float* cd_h = h_buf[1];
    float* mk_h = h_buf[2];

    hipMemsetAsync(stat_big, 0, 3 * 2176 * sizeof(float), stream);
    hipMemsetAsync(W2t, 0, (size_t)NP * KP * 2, stream);

    stats3_kernel<<<dim3(64, 1, 3), 256, 0, stream>>>(P);
    prep3_kernel<<<dim3(32, 3), 256, 0, stream>>>(P);
    subnet3_kernel<<<dim3(256, 3), 256, 0, stream>>>(P);

    build_both<<<NB + 1089, 192, 0, stream>>>(mk_h, us_h, p1, Wf1, W2t);

    gemm_kernel<<<dim3(NB / 128, NP / 128), 256, 0, stream>>>(p1, W2t, S);

    epilogue_kernel<<<NB / 4, 256, 0, stream>>>(S, cd_h, bf1, Wf2, bf2, out);
}

// Round 7
// 261.776 us; speedup vs baseline: 1.3858x; 1.0345x over previous
//
#include <hip/hip_runtime.h>
#include <hip/hip_bf16.h>
#include <math.h>

typedef __hip_bfloat16 bf16;
typedef __attribute__((ext_vector_type(4))) float f32x4;
typedef __attribute__((ext_vector_type(8))) short s16x8;

#define NB 8192
#define KP 1120   // padded K: 1089 -> 35*32
#define NP 1152   // padded N: 1089 -> 9*128

struct SubP {
    const float* x; const float* gamma; const float* beta;
    const float* W1; const float* b1; const float* W2; const float* b2;
    const float* W3; const float* b3;
    float* sum; float* sumsq; float* a; float* b1p; float* hout;
    int F;
};
struct SubP3 { SubP s[3]; };

// ---------------- BatchNorm stats: 64 rows/block, grid (128,3) ----------------
__global__ void __launch_bounds__(256) stats3_kernel(SubP3 P) {
    const SubP p = P.s[blockIdx.z];
    int t = threadIdx.x;
    int row0 = blockIdx.x * 64;
    if (p.F == 1024) {
        f32x4 s = {0.f, 0.f, 0.f, 0.f}, s2 = {0.f, 0.f, 0.f, 0.f};
        const float* xp = p.x + (size_t)row0 * 1024 + t * 4;
        #pragma unroll 8
        for (int r = 0; r < 64; r++) {
            f32x4 v = *(const f32x4*)(xp + (size_t)r * 1024);
            s += v; s2 += v * v;
        }
        int f = t * 4;
        #pragma unroll
        for (int e = 0; e < 4; e++) {
            atomicAdd(&p.sum[f + e], s[e]);
            atomicAdd(&p.sumsq[f + e], s2[e]);
        }
    } else {
        __shared__ float ls[16], ls2[16];
        if (t < 16) { ls[t] = 0.f; ls2[t] = 0.f; }
        __syncthreads();
        int F = p.F;
        for (int idx = t; idx < 64 * F; idx += 256) {
            float v = p.x[(size_t)row0 * F + idx];
            int f = idx % 10;            // row0*F ≡ 0 (mod F)
            atomicAdd(&ls[f], v);
            atomicAdd(&ls2[f], v * v);
        }
        __syncthreads();
        if (t < F) { atomicAdd(&p.sum[t], ls[t]); atomicAdd(&p.sumsq[t], ls2[t]); }
    }
}

// ---------------- finalize stats: a[f]; partial c@W1 fold -> atomic b1p ----------------
__global__ void prep3_kernel(SubP3 P) {
    const SubP p = P.s[blockIdx.y];
    int f0 = blockIdx.x * 32;
    if (f0 >= p.F) return;
    int t = threadIdx.x;
    __shared__ float c_sh[32];
    __shared__ float red[8][33];
    int fc = p.F - f0; if (fc > 32) fc = 32;
    if (t < 32) {
        float c = 0.f;
        if (t < fc) {
            int f = f0 + t;
            float mu  = p.sum[f]   * (1.f / 8192.f);
            float var = p.sumsq[f] * (1.f / 8192.f) - mu * mu;
            float a = p.gamma[f] * rsqrtf(var + 1e-5f);
            p.a[f] = a;
            c = p.beta[f] - mu * a;
        }
        c_sh[t] = c;
    }
    __syncthreads();
    int h = t & 31, g = t >> 5;
    float s = 0.f;
    for (int fi = g; fi < fc; fi += 8)
        s += c_sh[fi] * p.W1[(size_t)(f0 + fi) * 32 + h];
    red[g][h] = s;
    __syncthreads();
    if (t < 32) {
        float tot = 0.f;
        #pragma unroll
        for (int gg = 0; gg < 8; gg++) tot += red[gg][t];
        atomicAdd(&p.b1p[t], tot);
    }
}

// ---------------- Subnet MLP: 32 rows/block, 4h x 8r tile, k-split 8 ----------------
// Heavy path (F=1024): 128-k chunks, register prefetch of next X/W tiles (pipelined).
// Conflict-free hot reads: Xt stride 132, rows rg+4ri -> 8 addr groups x b128 = 32 banks,
// 8-lane broadcast; Wt stride 36, wave-uniform kk -> 8 addr groups, broadcast.
__global__ void __launch_bounds__(256) subnet3_kernel(SubP3 P) {
    const SubP p = P.s[blockIdx.y];
    const int F = p.F;
    __shared__ float smem[8832];
    float* Red = smem;            // 3 x [32][36] = 3456
    float* H1  = smem + 3456;     // [32][36] -> 4608
    float* W23 = smem + 4608;     // [32][33] -> 5664
    float* H2  = smem;            // [32][36]

    int t = threadIdx.x;
    int row0 = blockIdx.x * 32;
    int kg = t >> 6;
    int lane = t & 63;
    int hg = lane & 7, h0 = hg * 4;
    int rg = (lane >> 3) & 3;
    int ks = lane >> 5;

    float acc[4][8] = {};         // [hi][ri], rows rg + 4*ri

    if (F == 1024) {
        float* Xt = smem;             // [32][132] = 4224
        float* Wt = smem + 4224;      // [128][36] = 4608 -> 8832
        int xr = t >> 3, xc = (t & 7) * 16;
        int wk = t >> 1, wh = (t & 1) * 16;
        const float* xbase = p.x + (size_t)row0 * 1024;
        f32x4 xp[4], wp[4]; float av;
        #pragma unroll
        for (int i = 0; i < 4; i++) xp[i] = *(const f32x4*)&xbase[(size_t)xr * 1024 + xc + i * 4];
        #pragma unroll
        for (int i = 0; i < 4; i++) wp[i] = *(const f32x4*)&p.W1[(size_t)wk * 32 + wh + i * 4];
        av = p.a[wk];
        int kb = (kg * 2 + ks) * 16;
        for (int c = 0; c < 8; c++) {
            __syncthreads();          // prev chunk's reads done
            #pragma unroll
            for (int i = 0; i < 4; i++) *(f32x4*)&Xt[xr * 132 + xc + i * 4] = xp[i];
            #pragma unroll
            for (int i = 0; i < 4; i++) *(f32x4*)&Wt[wk * 36 + wh + i * 4] = wp[i] * av;
            if (c < 7) {
                int k0 = (c + 1) * 128;
                #pragma unroll
                for (int i = 0; i < 4; i++) xp[i] = *(const f32x4*)&xbase[(size_t)xr * 1024 + k0 + xc + i * 4];
                #pragma unroll
                for (int i = 0; i < 4; i++) wp[i] = *(const f32x4*)&p.W1[(size_t)(k0 + wk) * 32 + wh + i * 4];
                av = p.a[k0 + wk];
            }
            __syncthreads();          // tiles ready
            #pragma unroll
            for (int s = 0; s < 4; s++) {
                int kk = kb + s * 4;
                f32x4 wv[4], xv[8];
                #pragma unroll
                for (int j = 0; j < 4; j++)  wv[j]  = *(const f32x4*)&Wt[(kk + j) * 36 + h0];
                #pragma unroll
                for (int ri = 0; ri < 8; ri++) xv[ri] = *(const f32x4*)&Xt[(rg + 4 * ri) * 132 + kk];
                #pragma unroll
                for (int j = 0; j < 4; j++)
                    #pragma unroll
                    for (int hi = 0; hi < 4; hi++) {
                        float w = wv[j][hi];
                        #pragma unroll
                        for (int ri = 0; ri < 8; ri++)
                            acc[hi][ri] = fmaf(w, xv[ri][j], acc[hi][ri]);
                    }
            }
        }
    } else {
        float* Xt = smem;             // [32][68]
        float* Wt = smem + 2176;      // [64][36]
        int kbase = (kg * 2 + ks) * 8;
        for (int k0 = 0; k0 < F; k0 += 64) {
            int kc = F - k0; if (kc > 64) kc = 64;
            int kcp = (kc + 3) & ~3;
            __syncthreads();
            for (int idx = t; idx < 32 * kcp; idx += 256) {
                int r = idx / kcp, kk = idx - r * kcp;
                Xt[r * 68 + kk] = (kk < kc) ? p.x[(size_t)(row0 + r) * F + k0 + kk] : 0.f;
            }
            for (int idx = t; idx < kcp * 32; idx += 256) {
                int kk = idx >> 5, hh = idx & 31;
                Wt[kk * 36 + hh] = (kk < kc) ? p.a[k0 + kk] * p.W1[(size_t)(k0 + kk) * 32 + hh] : 0.f;
            }
            __syncthreads();
            #pragma unroll
            for (int s = 0; s < 2; s++) {
                int kk = kbase + s * 4;
                if (kk < kcp) {
                    f32x4 wv[4], xv[8];
                    #pragma unroll
                    for (int j = 0; j < 4; j++)  wv[j]  = *(const f32x4*)&Wt[(kk + j) * 36 + h0];
                    #pragma unroll
                    for (int ri = 0; ri < 8; ri++) xv[ri] = *(const f32x4*)&Xt[(rg + 4 * ri) * 68 + kk];
                    #pragma unroll
                    for (int j = 0; j < 4; j++)
                        #pragma unroll
                        for (int hi = 0; hi < 4; hi++) {
                            float w = wv[j][hi];
                            #pragma unroll
                            for (int ri = 0; ri < 8; ri++)
                                acc[hi][ri] = fmaf(w, xv[ri][j], acc[hi][ri]);
                        }
                }
            }
        }
    }
    // merge the two lane-half k-slices in-register
    #pragma unroll
    for (int hi = 0; hi < 4; hi++)
        #pragma unroll
        for (int ri = 0; ri < 8; ri++)
            acc[hi][ri] += __shfl_xor(acc[hi][ri], 32);
    __syncthreads();                              // S1: Xt/Wt dead
    if (kg > 0 && ks == 0) {
        #pragma unroll
        for (int ri = 0; ri < 8; ri++) {
            int r = rg + 4 * ri;
            f32x4 v = {acc[0][ri], acc[1][ri], acc[2][ri], acc[3][ri]};
            *(f32x4*)&Red[(kg - 1) * 1152 + r * 36 + h0] = v;
        }
    }
    for (int idx = t; idx < 1024; idx += 256) W23[(idx >> 5) * 33 + (idx & 31)] = p.W2[idx];
    __syncthreads();                              // S2: Red + W2 ready
    if (kg == 0 && ks == 0) {
        f32x4 b;
        #pragma unroll
        for (int hi = 0; hi < 4; hi++) b[hi] = p.b1[h0 + hi] + p.b1p[h0 + hi];
        #pragma unroll
        for (int ri = 0; ri < 8; ri++) {
            int r = rg + 4 * ri;
            f32x4 v = {acc[0][ri], acc[1][ri], acc[2][ri], acc[3][ri]};
            #pragma unroll
            for (int pp = 0; pp < 3; pp++)
                v += *(const f32x4*)&Red[pp * 1152 + r * 36 + h0];
            v += b;
            #pragma unroll
            for (int hi = 0; hi < 4; hi++)
                H1[r * 36 + h0 + hi] = fmaxf(v[hi], 0.f);
        }
    }
    __syncthreads();                              // S3: H1 ready
    int h = t & 31, rq = t >> 5;                  // 8 groups x 4 rows
    {
        float a2[4] = {};
        for (int q = 0; q < 32; q++) {
            float w = W23[q * 33 + h];
            #pragma unroll
            for (int i = 0; i < 4; i++) a2[i] += H1[(rq * 4 + i) * 36 + q] * w;
        }
        float bv = p.b2[h];
        #pragma unroll
        for (int i = 0; i < 4; i++) H2[(rq * 4 + i) * 36 + h] = fmaxf(a2[i] + bv, 0.f);
    }
    __syncthreads();                              // S4
    for (int idx = t; idx < 1024; idx += 256) W23[(idx >> 5) * 33 + (idx & 31)] = p.W3[idx];
    __syncthreads();                              // S5
    {
        float a3[4] = {};
        for (int q = 0; q < 32; q++) {
            float w = W23[q * 33 + h];
            #pragma unroll
            for (int i = 0; i < 4; i++) a3[i] += H2[(rq * 4 + i) * 36 + q] * w;
        }
        float bv = p.b3[h];
        #pragma unroll
        for (int i = 0; i < 4; i++)
            p.hout[(size_t)(row0 + rq * 4 + i) * 32 + h] = fmaxf(a3[i] + bv, 0.f);
    }
}

// ---------------- p1 build + W2t transpose (incl. K-pad zeroing), one launch ----------------
__global__ void build_both(const float* __restrict__ mk_h, const float* __restrict__ us_h,
                           bf16* __restrict__ p1,
                           const float* __restrict__ Wf1, bf16* __restrict__ W2t) {
    int blk = blockIdx.x;
    int t = threadIdx.x;
    if (blk < NB) {
        int b = blk;
        __shared__ float mk1[33], us1[33];
        if (t == 0) { mk1[0] = 1.f; us1[0] = 1.f; }
        if (t < 32) mk1[t + 1] = mk_h[(size_t)b * 32 + t];
        else if (t < 64) us1[t - 31] = us_h[(size_t)b * 32 + (t - 32)];
        __syncthreads();
        if (t < 140) {
            int base = t * 8;
            s16x8 v;
            #pragma unroll
            for (int e = 0; e < 8; e++) {
                int idx = base + e;
                float val = 0.f;
                if (idx < 1089) {
                    int k = idx / 33, i = idx - k * 33;
                    val = mk1[k] * us1[i];
                }
                __hip_bfloat16 hb = __float2bfloat16(val);
                v[e] = *(short*)&hb;
            }
            *(s16x8*)(p1 + (size_t)b * KP + base) = v;
        }
    } else {
        int kj = blk - NB;
        int k = kj / 33, j = kj - k * 33;
        __shared__ float tile[1089];
        const float* src = Wf1 + (size_t)k * 35937 + (size_t)j * 1089;  // [i][o] contiguous
        for (int idx = t; idx < 1089; idx += 192) tile[idx] = src[idx];
        __syncthreads();
        for (int idx = t; idx < 1089; idx += 192) {
            int o = idx / 33, i = idx - o * 33;
            W2t[(size_t)(j * 33 + o) * KP + k * 33 + i] = __float2bfloat16(tile[i * 33 + o]);
        }
        if (k == 0) {
            // zero the K-pad (kk 1089..1119) for this j's 33 n-rows
            bf16 z = __float2bfloat16(0.f);
            for (int idx = t; idx < 33 * 31; idx += 192) {
                int o = idx / 31, kkp = 1089 + idx - o * 31;
                W2t[(size_t)(j * 33 + o) * KP + kkp] = z;
            }
        }
    }
}

// ---------------- Main GEMM: S[8192,1152] = p1 @ W2t^T (bf16 MFMA, m97-style) ----------------
__global__ void __launch_bounds__(256) gemm_kernel(const bf16* __restrict__ A,   // [NB][KP]
                                                   const bf16* __restrict__ Bt,  // [NP][KP]
                                                   bf16* __restrict__ S) {       // [NB][NP]
    __shared__ __align__(16) bf16 As[128 * 32];
    __shared__ __align__(16) bf16 Bs[128 * 32];
    int t = threadIdx.x;
    int m0 = blockIdx.x * 128;
    int n0 = blockIdx.y * 128;
    int wave = t >> 6, lane = t & 63;
    int wm = (wave & 1) * 64, wn = (wave >> 1) * 64;
    int fr = lane & 15;
    int kg = (lane >> 4) * 8;

    int lr = lane >> 2;
    int lk = (lane & 3) * 8;
    const bf16* Ag = A  + (size_t)(m0 + wave * 32 + lr) * KP + lk;
    const bf16* Bg = Bt + (size_t)(n0 + wave * 32 + lr) * KP + lk;
    bf16* AsW = As + wave * 32 * 32;
    bf16* BsW = Bs + wave * 32 * 32;

    f32x4 acc[4][4] = {};

    for (int k0 = 0; k0 < KP; k0 += 32) {
        __syncthreads();
        __builtin_amdgcn_global_load_lds(
            (const __attribute__((address_space(1))) void*)(Ag + k0),
            (__attribute__((address_space(3))) void*)(AsW), 16, 0, 0);
        __builtin_amdgcn_global_load_lds(
            (const __attribute__((address_space(1))) void*)(Ag + k0 + 16 * KP),
            (__attribute__((address_space(3))) void*)(AsW + 16 * 32), 16, 0, 0);
        __builtin_amdgcn_global_load_lds(
            (const __attribute__((address_space(1))) void*)(Bg + k0),
            (__attribute__((address_space(3))) void*)(BsW), 16, 0, 0);
        __builtin_amdgcn_global_load_lds(
            (const __attribute__((address_space(1))) void*)(Bg + k0 + 16 * KP),
            (__attribute__((address_space(3))) void*)(BsW + 16 * 32), 16, 0, 0);
        __syncthreads();
        s16x8 bfr[4];
        #pragma unroll
        for (int nt = 0; nt < 4; nt++)
            bfr[nt] = *(const s16x8*)(Bs + (wn + nt * 16 + fr) * 32 + kg);
        #pragma unroll
        for (int mt = 0; mt < 4; mt++) {
            s16x8 af = *(const s16x8*)(As + (wm + mt * 16 + fr) * 32 + kg);
            #pragma unroll
            for (int nt = 0; nt < 4; nt++)
                acc[mt][nt] = __builtin_amdgcn_mfma_f32_16x16x32_bf16(af, bfr[nt], acc[mt][nt], 0, 0, 0);
        }
    }
    int col = lane & 15, rowg = (lane >> 4) * 4;
    #pragma unroll
    for (int mt = 0; mt < 4; mt++)
        #pragma unroll
        for (int nt = 0; nt < 4; nt++)
            #pragma unroll
            for (int r = 0; r < 4; r++) {
                int gr = m0 + wm + mt * 16 + rowg + r;
                int gc = n0 + wn + nt * 16 + col;
                S[(size_t)gr * NP + gc] = __float2bfloat16(acc[mt][nt][r]);
            }
}

// ---------------- Epilogue: stage S rows as bf16 in LDS, contract j, 33x5 + sigmoid ----------
__global__ void __launch_bounds__(256) epilogue_kernel(const bf16* __restrict__ S,
                                const float* __restrict__ cd_h,
                                const float* __restrict__ bf1, const float* __restrict__ Wf2,
                                const float* __restrict__ bf2, float* __restrict__ out) {
    int w = threadIdx.x >> 6;
    int lane = threadIdx.x & 63;
    int b = blockIdx.x * 4 + w;
    __shared__ __align__(16) unsigned short Sl[4][1152];
    __shared__ float cdsh[4][33];
    __shared__ float hsh[4][40];
    // coalesced stage: wave reads its row as 16B chunks (144 chunks of 8 bf16)
    const bf16* Srow = S + (size_t)b * NP;
    #pragma unroll
    for (int pass = 0; pass < 3; pass++) {
        int idx = lane + pass * 64;
        if (idx < 144)
            *(s16x8*)&Sl[w][idx * 8] = *(const s16x8*)(Srow + idx * 8);
    }
    if (lane == 0) cdsh[w][0] = 1.f;
    if (lane < 32) cdsh[w][lane + 1] = cd_h[(size_t)b * 32 + lane];
    __syncthreads();
    if (lane < 33) {
        float acc = bf1[lane];
        #pragma unroll 3
        for (int j = 0; j < 33; j++) {
            unsigned short sv = Sl[w][j * 33 + lane];
            acc += cdsh[w][j] * __bfloat162float(*(bf16*)&sv);
        }
        hsh[w][lane] = fmaxf(acc, 0.f);
    }
    __syncthreads();
    if (lane < 5) {
        float o = bf2[lane];
        for (int q = 0; q < 33; q++) o += hsh[w][q] * Wf2[q * 5 + lane];
        out[(size_t)b * 5 + lane] = 1.f / (1.f + expf(-o));
    }
}

extern "C" void kernel_launch(void* const* d_in, const int* in_sizes, int n_in,
                              void* d_out, int out_size, void* d_ws, size_t ws_size,
                              hipStream_t stream) {
    const float* US_x     = (const float*)d_in[0];
    const float* CDFI_x   = (const float*)d_in[1];
    const float* marker_x = (const float*)d_in[2];
    const float* Wf1      = (const float*)d_in[27];
    const float* bf1      = (const float*)d_in[28];
    const float* Wf2      = (const float*)d_in[29];
    const float* bf2      = (const float*)d_in[30];
    float* out = (float*)d_out;

    char* ws = (char*)d_ws;
    size_t off = 0;
    auto alloc = [&](size_t bytes) -> void* {
        void* p = ws + off;
        off = (off + bytes + 255) & ~(size_t)255;
        return p;
    };

    // per subnet: sum[1024] | sumsq[1024] | b1p_acc[128]  (all zeroed)
    float* stat_big = (float*)alloc(3 * 2176 * sizeof(float));
    float* a_buf[3], *h_buf[3];
    for (int i = 0; i < 3; i++) {
        a_buf[i] = (float*)alloc(1024 * 4);
        h_buf[i] = (float*)alloc((size_t)NB * 32 * 4);
    }
    bf16*  p1   = (bf16*)alloc((size_t)NB * KP * 2);
    bf16*  W2t  = (bf16*)alloc((size_t)NP * KP * 2);
    bf16*  S    = (bf16*)alloc((size_t)NB * NP * 2);

    SubP3 P;
    const float* xs[3] = {US_x, CDFI_x, marker_x};
    int Fs[3] = {1024, 1024, 10};
    for (int i = 0; i < 3; i++) {
        int base = 3 + i * 8;
        P.s[i].x     = xs[i];
        P.s[i].gamma = (const float*)d_in[base + 0];
        P.s[i].beta  = (const float*)d_in[base + 1];
        P.s[i].W1    = (const float*)d_in[base + 2];
        P.s[i].b1    = (const float*)d_in[base + 3];
        P.s[i].W2    = (const float*)d_in[base + 4];
        P.s[i].b2    = (const float*)d_in[base + 5];
        P.s[i].W3    = (const float*)d_in[base + 6];
        P.s[i].b3    = (const float*)d_in[base + 7];
        P.s[i].sum   = stat_big + i * 2176;
        P.s[i].sumsq = stat_big + i * 2176 + 1024;
        P.s[i].b1p   = stat_big + i * 2176 + 2048;
        P.s[i].a     = a_buf[i];
        P.s[i].hout  = h_buf[i];
        P.s[i].F     = Fs[i];
    }

    float* us_h = h_buf[0];
    float* cd_h = h_buf[1];
    float* mk_h = h_buf[2];

    hipMemsetAsync(stat_big, 0, 3 * 2176 * sizeof(float), stream);

    stats3_kernel<<<dim3(128, 1, 3), 256, 0, stream>>>(P);
    prep3_kernel<<<dim3(32, 3), 256, 0, stream>>>(P);
    subnet3_kernel<<<dim3(256, 3), 256, 0, stream>>>(P);

    build_both<<<NB + 1089, 192, 0, stream>>>(mk_h, us_h, p1, Wf1, W2t);

    gemm_kernel<<<dim3(NB / 128, NP / 128), 256, 0, stream>>>(p1, W2t, S);

    epilogue_kernel<<<NB / 4, 256, 0, stream>>>(S, cd_h, bf1, Wf2, bf2, out);
}